// Round 5
// baseline (435.331 us; speedup 1.0000x reference)
//
#include <hip/hip_runtime.h>
#include <stdint.h>

#define T_ 4
#define B_ 32
#define N_ 256
#define C_ 384
#define H_ 8
#define D_ 48
#define ROWS (B_*N_)                  // 8192 (b,n) rows
#define SCALE_F 0.051031036307982884f // 384^-0.5

// workspace layout (bytes); all spike tensors stored as bf16 (exact for {0,1})
#define QS_OFF 0u
#define KS_OFF 25165824u
#define VS_OFF 50331648u
#define AS_OFF 75497472u
#define WH_OFF 0u
#define WM_OFF 294912u
#define WL_OFF 589824u

typedef __bf16 bf16x8 __attribute__((ext_vector_type(8)));
typedef float  f32x4  __attribute__((ext_vector_type(4)));

__device__ __forceinline__ void split3(float s, uint32_t& h, uint32_t& m, uint32_t& l) {
    uint32_t u  = __float_as_uint(s);
    uint32_t hu = u & 0xffff0000u;
    float r1 = s - __uint_as_float(hu);
    uint32_t u1 = __float_as_uint(r1);
    uint32_t mu = u1 & 0xffff0000u;
    float r2 = r1 - __uint_as_float(mu);
    h = hu >> 16; m = mu >> 16; l = __float_as_uint(r2) >> 16;
}

// ---------------------------------------------------------------------------
// K0: exact 3-way split of w_q/w_k/w_v into bf16 planes (unchanged)
// ---------------------------------------------------------------------------
__global__ void k_wsplit3(const float* __restrict__ wq, const float* __restrict__ wk,
                          const float* __restrict__ wv, uint16_t* __restrict__ out)
{
    const int br = blockIdx.y;
    const float* __restrict__ w = (br==0)? wq : (br==1)? wk : wv;
    const int idx = blockIdx.x*256 + threadIdx.x;
    uint32_t h, m, l;
    split3(w[idx], h, m, l);
    uint16_t* base = out + (size_t)br*442368;
    base[idx] = (uint16_t)h;
    base[147456 + idx] = (uint16_t)m;
    base[294912 + idx] = (uint16_t)l;
}

#define SA 104   // LDS row stride (elems): 16B-aligned, spreads b128 over bank groups

// ---------------------------------------------------------------------------
// K1 v5: MFMA qkv GEMM + BN + LIF.
//  - A (x, split 3-way on the fly) staged through LDS with REGISTER PREFETCH
//    across the barrier (prefetch kt+1 issued before the MFMA burst of kt).
//  - B fragments loaded DIRECTLY from global w-planes (L2-resident, 16B/lane)
//    — no B LDS traffic at all.
//  - Same 6 products, same chain order as round 3 (bit-identical accums).
// Block: M=128 (4t x 32 bn-rows, t-major) x N=128 cols; 4 waves, tile 64x64.
// LDS = At[128][104] = 26.6 KB -> 3 blocks/CU at launch_bounds(256,3).
// ---------------------------------------------------------------------------
__global__ __launch_bounds__(256, 3) void k_qkv_v5(
    const float* __restrict__ x, const uint16_t* __restrict__ wbr,
    const float* __restrict__ bnq, const float* __restrict__ bnk, const float* __restrict__ bnv,
    uint16_t* __restrict__ qs, uint16_t* __restrict__ ks, uint16_t* __restrict__ vs)
{
    const int cb = blockIdx.x;
    const int branch = cb / 3;
    const int ct = cb - branch*3;
    const int c0 = ct * 128;
    const int bn0 = blockIdx.y * 32;
    const float* __restrict__ bnp_ = (branch==0)? bnq : (branch==1)? bnk : bnv;
    uint16_t* __restrict__ outp = (branch==0)? qs : (branch==1)? ks : vs;
    const uint16_t* __restrict__ wpl = wbr + (size_t)branch*442368;

    __shared__ __align__(16) uint16_t At[128][SA];   // [t*32+bnl][plane*32+k]

    const int tid  = threadIdx.x;
    const int wv   = tid >> 6;
    const int lane = tid & 63;
    const int l15  = lane & 15;
    const int quad = lane >> 4;
    const int q8   = quad * 8;
    const int rg   = wv >> 1;            // rg0 -> t0,t1 ; rg1 -> t2,t3
    const int wcol = (wv & 1) * 64;

    f32x4 acc[4][4];
    #pragma unroll
    for (int it=0; it<4; ++it)
        #pragma unroll
        for (int jt=0; jt<4; ++jt) acc[it][jt] = (f32x4){0.f,0.f,0.f,0.f};

    // A staging: thread -> (trow = t*32+bnl, half of 32k), 16 fp32 each
    const int trow = tid >> 1, half = tid & 1;
    const int tA = trow >> 5, bnlA = trow & 31;
    const float* xrow = x + ((size_t)(tA*ROWS + bn0 + bnlA))*C_ + half*16;

    // per-lane B fragment base addresses (row fixed per jt; k advances with kt)
    const uint16_t* bbase[4];
    #pragma unroll
    for (int jt=0; jt<4; ++jt)
        bbase[jt] = wpl + (size_t)(c0 + wcol + jt*16 + l15)*C_ + q8;

    // prefetch A(kt=0)
    float fe[16];
    #pragma unroll
    for (int s=0; s<4; ++s)
        *(float4*)&fe[4*s] = *(const float4*)(xrow + 4*s);

    for (int kt=0; kt<12; ++kt) {
        const int k0 = kt*32;
        __syncthreads();                  // prev-iter A-frag reads done
        {   // split prefetched regs, write 3 planes (6 x ds_write_b128)
            uint32_t hw[8], mw[8], lw[8];
            #pragma unroll
            for (int i=0; i<8; ++i) {
                const float s0 = fe[2*i], s1 = fe[2*i+1];
                const uint32_t h0 = __float_as_uint(s0) & 0xffff0000u;
                const uint32_t h1 = __float_as_uint(s1) & 0xffff0000u;
                const float r0 = s0 - __uint_as_float(h0);
                const float r1 = s1 - __uint_as_float(h1);
                const uint32_t m0 = __float_as_uint(r0) & 0xffff0000u;
                const uint32_t m1 = __float_as_uint(r1) & 0xffff0000u;
                const float p0 = r0 - __uint_as_float(m0);
                const float p1 = r1 - __uint_as_float(m1);
                hw[i] = (h0>>16) | h1;
                mw[i] = (m0>>16) | m1;
                lw[i] = (__float_as_uint(p0)>>16) | (__float_as_uint(p1) & 0xffff0000u);
            }
            *(uint4*)&At[trow][ 0 + half*16]     = make_uint4(hw[0],hw[1],hw[2],hw[3]);
            *(uint4*)&At[trow][ 0 + half*16 + 8] = make_uint4(hw[4],hw[5],hw[6],hw[7]);
            *(uint4*)&At[trow][32 + half*16]     = make_uint4(mw[0],mw[1],mw[2],mw[3]);
            *(uint4*)&At[trow][32 + half*16 + 8] = make_uint4(mw[4],mw[5],mw[6],mw[7]);
            *(uint4*)&At[trow][64 + half*16]     = make_uint4(lw[0],lw[1],lw[2],lw[3]);
            *(uint4*)&At[trow][64 + half*16 + 8] = make_uint4(lw[4],lw[5],lw[6],lw[7]);
        }
        __syncthreads();                  // A tile visible

        // prefetch A(kt+1) — in flight across the whole MFMA burst
        if (kt < 11) {
            const float* xn = xrow + (kt+1)*32;
            #pragma unroll
            for (int s=0; s<4; ++s)
                *(float4*)&fe[4*s] = *(const float4*)(xn + 4*s);
        }

        // B fragments direct from global (L2-hot, 16 B per lane per frag)
        bf16x8 bfr[4][3];
        #pragma unroll
        for (int jt=0; jt<4; ++jt) {
            bfr[jt][0] = *(const bf16x8*)(bbase[jt] + k0);             // h plane
            bfr[jt][1] = *(const bf16x8*)(bbase[jt] + 147456 + k0);    // m plane
            bfr[jt][2] = *(const bf16x8*)(bbase[jt] + 294912 + k0);    // l plane
        }
        // A fragments from LDS
        bf16x8 af[4][3];
        #pragma unroll
        for (int it=0; it<4; ++it) {
            const uint16_t* ar = &At[rg*64 + it*16 + l15][q8];
            af[it][0] = *(const bf16x8*)(ar);
            af[it][1] = *(const bf16x8*)(ar + 32);
            af[it][2] = *(const bf16x8*)(ar + 64);
        }
        #pragma unroll
        for (int jt=0; jt<4; ++jt) {
            #pragma unroll
            for (int it=0; it<4; ++it) {
                f32x4 a = acc[it][jt];
                a = __builtin_amdgcn_mfma_f32_16x16x32_bf16(af[it][0], bfr[jt][0], a, 0,0,0);
                a = __builtin_amdgcn_mfma_f32_16x16x32_bf16(af[it][0], bfr[jt][1], a, 0,0,0);
                a = __builtin_amdgcn_mfma_f32_16x16x32_bf16(af[it][1], bfr[jt][0], a, 0,0,0);
                a = __builtin_amdgcn_mfma_f32_16x16x32_bf16(af[it][0], bfr[jt][2], a, 0,0,0);
                a = __builtin_amdgcn_mfma_f32_16x16x32_bf16(af[it][1], bfr[jt][1], a, 0,0,0);
                a = __builtin_amdgcn_mfma_f32_16x16x32_bf16(af[it][2], bfr[jt][0], a, 0,0,0);
                acc[it][jt] = a;
            }
        }
    }

    // ---- epilogue: BN + LIF over t (identical to round-3 verified logic) ----
    __syncthreads();
    float* vex = (float*)&At[0][0];      // [bnl 0..31][cl 0..127] f32 = 16 KB

    #define STORE_SP(tt, sp) do { \
        if (branch == 2) { \
            const int h2 = cg / 48, dd = cg - h2*48; \
            const int bng = bn0 + bnl; \
            outp[((((size_t)(tt)*B_ + (bng>>8))*H_ + h2)*D_ + dd)*N_ + (bng&255)] = (sp); \
        } else { \
            outp[((size_t)((tt)*ROWS + bn0 + bnl))*C_ + cg] = (sp); \
        } \
    } while(0)

    if (rg == 0) {
        #pragma unroll
        for (int jt=0; jt<4; ++jt) {
            const int cl = wcol + jt*16 + l15;
            const int cg = c0 + cl;
            const float g = bnp_[cg], be = bnp_[C_+cg], mu = bnp_[2*C_+cg], va = bnp_[3*C_+cg];
            const float scl = g * (float)(1.0 / sqrt((double)(va + 1e-5f)));
            #pragma unroll
            for (int a=0; a<2; ++a)
                #pragma unroll
                for (int r=0; r<4; ++r) {
                    const int bnl = a*16 + quad*4 + r;
                    const float y0 = (acc[a  ][jt][r] - mu)*scl + be;   // t0
                    const float y1 = (acc[a+2][jt][r] - mu)*scl + be;   // t1
                    float v = 0.f;
                    float h = v + (y0 - v)*0.5f;
                    STORE_SP(0, (h >= 1.0f) ? (uint16_t)0x3f80 : (uint16_t)0);
                    v = (h >= 1.0f) ? 0.f : h;
                    h = v + (y1 - v)*0.5f;
                    STORE_SP(1, (h >= 1.0f) ? (uint16_t)0x3f80 : (uint16_t)0);
                    v = (h >= 1.0f) ? 0.f : h;
                    vex[bnl*128 + cl] = v;
                }
        }
    }
    __syncthreads();
    if (rg == 1) {
        #pragma unroll
        for (int jt=0; jt<4; ++jt) {
            const int cl = wcol + jt*16 + l15;
            const int cg = c0 + cl;
            const float g = bnp_[cg], be = bnp_[C_+cg], mu = bnp_[2*C_+cg], va = bnp_[3*C_+cg];
            const float scl = g * (float)(1.0 / sqrt((double)(va + 1e-5f)));
            #pragma unroll
            for (int a=0; a<2; ++a)
                #pragma unroll
                for (int r=0; r<4; ++r) {
                    const int bnl = a*16 + quad*4 + r;
                    const float y2 = (acc[a  ][jt][r] - mu)*scl + be;   // t2
                    const float y3 = (acc[a+2][jt][r] - mu)*scl + be;   // t3
                    float v = vex[bnl*128 + cl];
                    float h = v + (y2 - v)*0.5f;
                    STORE_SP(2, (h >= 1.0f) ? (uint16_t)0x3f80 : (uint16_t)0);
                    v = (h >= 1.0f) ? 0.f : h;
                    h = v + (y3 - v)*0.5f;
                    STORE_SP(3, (h >= 1.0f) ? (uint16_t)0x3f80 : (uint16_t)0);
                }
        }
    }
    #undef STORE_SP
}

// ---------------------------------------------------------------------------
// K2: MFMA attention + attn-LIF (unchanged — verified)
// ---------------------------------------------------------------------------
__global__ __launch_bounds__(256, 2) void k_attn(
    const uint16_t* __restrict__ qs, const uint16_t* __restrict__ ks, const uint16_t* __restrict__ vs,
    const float* __restrict__ rel, uint16_t* __restrict__ as_)
{
    const int bh = blockIdx.x;
    const int b = bh >> 3, h = bh & 7;
    const int i0 = blockIdx.y * 128;

    __shared__ __align__(16) uint16_t qt[128][72];
    __shared__ __align__(16) uint16_t kt[32][72];
    __shared__ __align__(16) uint16_t vT[48][40];
    __shared__ __align__(16) uint16_t sh[3][128][40];
    __shared__ float tab_s[384];

    const int tid  = threadIdx.x;
    const int wv_  = tid >> 6;
    const int lane = tid & 63;
    const int l15  = lane & 15;
    const int quad = lane >> 4;
    const int w32  = wv_ * 32;
    const int q8   = quad * 8;

    for (int l = tid; l < 383; l += 256) tab_s[l] = rel[(size_t)(i0 + l)*H_ + h];
    {
        const uint4 z = make_uint4(0,0,0,0);
        { const int row = tid >> 1, seg = tid & 1;
          *(uint4*)&qt[row][48 + seg*8] = z; }
        if (tid < 64) { const int row = tid >> 1, seg = tid & 1;
          *(uint4*)&kt[row][48 + seg*8] = z; }
    }

    float vst[2][3][4];
    #pragma unroll
    for (int a=0;a<2;++a)
        #pragma unroll
        for (int e=0;e<3;++e)
            #pragma unroll
            for (int r=0;r<4;++r) vst[a][e][r]=0.f;

    for (int t=0; t<4; ++t) {
        const int tb = t*B_ + b;
        __syncthreads();
        #pragma unroll
        for (int rep=0; rep<3; ++rep) {
            const int l = rep*256 + tid;
            const int row = l / 6, seg = l - 6*row;
            *(uint4*)&qt[row][seg*8] =
                *(const uint4*)(qs + ((size_t)(tb*N_ + i0 + row))*C_ + h*D_ + seg*8);
        }

        f32x4 pacc[2][3];
        #pragma unroll
        for (int a=0;a<2;++a)
            #pragma unroll
            for (int e=0;e<3;++e) pacc[a][e] = (f32x4){0.f,0.f,0.f,0.f};

        for (int j0 = 0; j0 < 256; j0 += 32) {
            __syncthreads();
            if (tid < 192) {
                const int row = tid / 6, seg = tid - 6*row;
                *(uint4*)&kt[row][seg*8] =
                    *(const uint4*)(ks + ((size_t)(tb*N_ + j0 + row))*C_ + h*D_ + seg*8);
            } else {
                const int l = tid - 192;
                #pragma unroll
                for (int rep=0; rep<3; ++rep) {
                    const int e = rep*64 + l;
                    const int d = e >> 2, seg = e & 3;
                    *(uint4*)&vT[d][seg*8] =
                        *(const uint4*)(vs + (((size_t)(tb*H_ + h))*D_ + d)*N_ + j0 + seg*8);
                }
            }
            __syncthreads();

            f32x4 sacc[2][2];
            #pragma unroll
            for (int a=0;a<2;++a)
                #pragma unroll
                for (int c2=0;c2<2;++c2) sacc[a][c2] = (f32x4){0.f,0.f,0.f,0.f};
            bf16x8 qa[2][2];
            #pragma unroll
            for (int it=0; it<2; ++it)
                #pragma unroll
                for (int ks_=0; ks_<2; ++ks_)
                    qa[it][ks_] = *(const bf16x8*)&qt[w32 + it*16 + l15][ks_*32 + q8];
            #pragma unroll
            for (int jt=0; jt<2; ++jt) {
                #pragma unroll
                for (int ks_=0; ks_<2; ++ks_) {
                    const bf16x8 kb = *(const bf16x8*)&kt[jt*16 + l15][ks_*32 + q8];
                    #pragma unroll
                    for (int it=0; it<2; ++it)
                        sacc[it][jt] = __builtin_amdgcn_mfma_f32_16x16x32_bf16(
                            qa[it][ks_], kb, sacc[it][jt], 0, 0, 0);
                }
            }

            #pragma unroll
            for (int it=0; it<2; ++it)
                #pragma unroll
                for (int jt=0; jt<2; ++jt) {
                    const int jl = jt*16 + l15;
                    const int jg = j0 + jl;
                    #pragma unroll
                    for (int r=0; r<4; ++r) {
                        const int il = w32 + it*16 + quad*4 + r;
                        const float s = sacc[it][jt][r] + tab_s[il - jg + 255];
                        uint32_t hh, mm, ll;
                        split3(s, hh, mm, ll);
                        sh[0][il][jl] = (uint16_t)hh;
                        sh[1][il][jl] = (uint16_t)mm;
                        sh[2][il][jl] = (uint16_t)ll;
                    }
                }

            bf16x8 vb[3];
            #pragma unroll
            for (int dt=0; dt<3; ++dt)
                vb[dt] = *(const bf16x8*)&vT[dt*16 + l15][q8];
            #pragma unroll
            for (int it=0; it<2; ++it)
                #pragma unroll
                for (int p=0; p<3; ++p) {
                    const bf16x8 sa = *(const bf16x8*)&sh[p][w32 + it*16 + l15][q8];
                    #pragma unroll
                    for (int dt=0; dt<3; ++dt)
                        pacc[it][dt] = __builtin_amdgcn_mfma_f32_16x16x32_bf16(
                            sa, vb[dt], pacc[it][dt], 0, 0, 0);
                }
        }

        #pragma unroll
        for (int it=0; it<2; ++it)
            #pragma unroll
            for (int dt=0; dt<3; ++dt)
                #pragma unroll
                for (int r=0; r<4; ++r) {
                    const float xin = pacc[it][dt][r] * SCALE_F;
                    float v = vst[it][dt][r];
                    const float hh = v + (xin - v)*0.5f;
                    const uint16_t sp = (hh >= 1.0f) ? (uint16_t)0x3f80 : (uint16_t)0;
                    vst[it][dt][r] = (hh >= 1.0f) ? 0.f : hh;
                    const int ig = i0 + w32 + it*16 + quad*4 + r;
                    const int c  = h*D_ + dt*16 + l15;
                    as_[((size_t)(tb*N_ + ig))*C_ + c] = sp;
                }
    }
}

// ---------------------------------------------------------------------------
// K2.5: exact 3-way split of w_p (unchanged)
// ---------------------------------------------------------------------------
__global__ void k_wsplit(const float* __restrict__ wp,
                         uint16_t* __restrict__ wh, uint16_t* __restrict__ wm,
                         uint16_t* __restrict__ wl)
{
    const int idx = blockIdx.x*256 + threadIdx.x;
    uint32_t h, m, l;
    split3(wp[idx], h, m, l);
    wh[idx] = (uint16_t)h; wm[idx] = (uint16_t)m; wl[idx] = (uint16_t)l;
}

// ---------------------------------------------------------------------------
// K3: MFMA proj (unchanged — verified)
// ---------------------------------------------------------------------------
__global__ __launch_bounds__(256, 2) void k_proj(
    const uint16_t* __restrict__ as_,
    const uint16_t* __restrict__ wh, const uint16_t* __restrict__ wm,
    const uint16_t* __restrict__ wl,
    const float* __restrict__ bnp, float* __restrict__ out)
{
    const int r0 = blockIdx.x * 64;
    const int c0 = blockIdx.y * 96;

    __shared__ __align__(16) uint16_t At[4][64][40];
    __shared__ __align__(16) uint16_t Bt[3][96][40];

    const int tid  = threadIdx.x;
    const int wv_  = tid >> 6;
    const int lane = tid & 63;
    const int l15  = lane & 15;
    const int quad = lane >> 4;
    const int q8   = quad * 8;

    f32x4 acc[4][6];
    #pragma unroll
    for (int t=0;t<4;++t)
        #pragma unroll
        for (int nt=0;nt<6;++nt) acc[t][nt] = (f32x4){0.f,0.f,0.f,0.f};

    for (int kstep=0; kstep<12; ++kstep) {
        const int k0 = kstep*32;
        __syncthreads();
        #pragma unroll
        for (int rep=0; rep<4; ++rep) {
            const int l = rep*256 + tid;
            const int t = l >> 8, row = (l >> 2) & 63, seg = l & 3;
            *(uint4*)&At[t][row][seg*8] =
                *(const uint4*)(as_ + ((size_t)(t*ROWS + r0 + row))*C_ + k0 + seg*8);
        }
        for (int l = tid; l < 1152; l += 256) {
            const int p = l / 384, rem = l - 384*p;
            const int c = rem >> 2, seg = rem & 3;
            const uint16_t* src = (p==0)? wh : (p==1)? wm : wl;
            *(uint4*)&Bt[p][c][seg*8] =
                *(const uint4*)(src + (size_t)(c0 + c)*C_ + k0 + seg*8);
        }
        __syncthreads();

        bf16x8 af[4];
        #pragma unroll
        for (int t=0;t<4;++t)
            af[t] = *(const bf16x8*)&At[t][wv_*16 + l15][q8];
        #pragma unroll
        for (int nt=0; nt<6; ++nt) {
            #pragma unroll
            for (int p=0; p<3; ++p) {
                const bf16x8 bf_ = *(const bf16x8*)&Bt[p][nt*16 + l15][q8];
                #pragma unroll
                for (int t=0;t<4;++t)
                    acc[t][nt] = __builtin_amdgcn_mfma_f32_16x16x32_bf16(
                        af[t], bf_, acc[t][nt], 0, 0, 0);
            }
        }
    }

    #pragma unroll
    for (int nt=0; nt<6; ++nt) {
        const int c = c0 + nt*16 + l15;
        const float g = bnp[c], be = bnp[C_+c], mu = bnp[2*C_+c], va = bnp[3*C_+c];
        const float scl = g * (float)(1.0 / sqrt((double)(va + 1e-5f)));
        #pragma unroll
        for (int r=0; r<4; ++r) {
            const int rg = r0 + wv_*16 + quad*4 + r;
            float v = 0.f;
            #pragma unroll
            for (int t=0; t<4; ++t) {
                const float y  = (acc[t][nt][r] - mu)*scl + be;
                const float hh = v + (y - v)*0.5f;
                const float sp = (hh >= 1.0f) ? 1.0f : 0.f;
                v = (hh >= 1.0f) ? 0.f : hh;
                out[((size_t)(t*ROWS + rg))*C_ + c] = sp;
            }
        }
    }
}

extern "C" void kernel_launch(void* const* d_in, const int* in_sizes, int n_in,
                              void* d_out, int out_size, void* d_ws, size_t ws_size,
                              hipStream_t stream) {
    const float* x   = (const float*)d_in[0];
    const float* wq  = (const float*)d_in[1];
    const float* wk  = (const float*)d_in[2];
    const float* wv  = (const float*)d_in[3];
    const float* wp  = (const float*)d_in[4];
    const float* bnq = (const float*)d_in[5];
    const float* bnk = (const float*)d_in[6];
    const float* bnv = (const float*)d_in[7];
    const float* bnp = (const float*)d_in[8];
    const float* rel = (const float*)d_in[9];
    float* out = (float*)d_out;
    uint8_t* ws = (uint8_t*)d_ws;
    uint16_t* qs  = (uint16_t*)(ws + QS_OFF);
    uint16_t* ks  = (uint16_t*)(ws + KS_OFF);
    uint16_t* vs  = (uint16_t*)(ws + VS_OFF);
    uint16_t* as_ = (uint16_t*)(ws + AS_OFF);
    uint16_t* wbr = (uint16_t*)(ws + AS_OFF);      // branch w-planes: dead once k_attn writes as_
    uint16_t* wh  = (uint16_t*)(ws + WH_OFF);
    uint16_t* wm  = (uint16_t*)(ws + WM_OFF);
    uint16_t* wl  = (uint16_t*)(ws + WL_OFF);

    k_wsplit3<<<dim3(576, 3), 256, 0, stream>>>(wq, wk, wv, wbr);
    k_qkv_v5 <<<dim3(9, 256), 256, 0, stream>>>(x, wbr, bnq, bnk, bnv, qs, ks, vs);
    k_attn   <<<dim3(256, 2), 256, 0, stream>>>(qs, ks, vs, rel, as_);
    k_wsplit <<<dim3(576),    256, 0, stream>>>(wp, wh, wm, wl);
    k_proj   <<<dim3(128, 4), 256, 0, stream>>>(as_, wh, wm, wl, bnp, out);
}

// Round 6
// 375.661 us; speedup vs baseline: 1.1588x; 1.1588x over previous
//
#include <hip/hip_runtime.h>
#include <stdint.h>

#define T_ 4
#define B_ 32
#define N_ 256
#define C_ 384
#define H_ 8
#define D_ 48
#define ROWS (B_*N_)                  // 8192 (b,n) rows
#define SCALE_F 0.051031036307982884f // 384^-0.5

// workspace layout (bytes); all spike tensors stored as bf16 (exact for {0,1})
#define QS_OFF 0u
#define KS_OFF 25165824u
#define VS_OFF 50331648u
#define AS_OFF 75497472u
#define WH_OFF 0u
#define WM_OFF 294912u
#define WL_OFF 589824u

typedef __bf16 bf16x8 __attribute__((ext_vector_type(8)));
typedef float  f32x4  __attribute__((ext_vector_type(4)));

__device__ __forceinline__ void split3(float s, uint32_t& h, uint32_t& m, uint32_t& l) {
    uint32_t u  = __float_as_uint(s);
    uint32_t hu = u & 0xffff0000u;
    float r1 = s - __uint_as_float(hu);
    uint32_t u1 = __float_as_uint(r1);
    uint32_t mu = u1 & 0xffff0000u;
    float r2 = r1 - __uint_as_float(mu);
    h = hu >> 16; m = mu >> 16; l = __float_as_uint(r2) >> 16;
}

// ---------------------------------------------------------------------------
// K0: exact 3-way split of w_q/w_k/w_v into bf16 planes (unchanged)
// ---------------------------------------------------------------------------
__global__ void k_wsplit3(const float* __restrict__ wq, const float* __restrict__ wk,
                          const float* __restrict__ wv, uint16_t* __restrict__ out)
{
    const int br = blockIdx.y;
    const float* __restrict__ w = (br==0)? wq : (br==1)? wk : wv;
    const int idx = blockIdx.x*256 + threadIdx.x;
    uint32_t h, m, l;
    split3(w[idx], h, m, l);
    uint16_t* base = out + (size_t)br*442368;
    base[idx] = (uint16_t)h;
    base[147456 + idx] = (uint16_t)m;
    base[294912 + idx] = (uint16_t)l;
}

#define SA 104   // A-tile LDS row stride (padded, bank-spread for b128)

// ---------------------------------------------------------------------------
// K1 v6: MFMA qkv GEMM + BN + LIF.
//  - A: fp32 x register-prefetched across the barrier, split3 on the fly,
//    ds_write to padded At (round-5-verified path).
//  - B: staged via global_load_lds width=16 DMA into UNPADDED per-plane
//    buffers Bp[3][128][32] (DMA needs lane-contiguous dest; wave frag reads
//    then cover a contiguous 1KB -> minimum-pass). No VGPR round trip.
//  - Same 6 products, same chain order as round 3 (bit-identical accums).
// Block: M=128 (4t x 32 bn-rows) x N=128; 4 waves, wave tile 64x64.
// LDS = 26.6KB (At) + 24KB (Bp) = 50.2KB -> 3 blocks/CU.
// ---------------------------------------------------------------------------
__global__ __launch_bounds__(256, 3) void k_qkv_v6(
    const float* __restrict__ x, const uint16_t* __restrict__ wbr,
    const float* __restrict__ bnq, const float* __restrict__ bnk, const float* __restrict__ bnv,
    uint16_t* __restrict__ qs, uint16_t* __restrict__ ks, uint16_t* __restrict__ vs)
{
    const int cb = blockIdx.x;
    const int branch = cb / 3;
    const int ct = cb - branch*3;
    const int c0 = ct * 128;
    const int bn0 = blockIdx.y * 32;
    const float* __restrict__ bnp_ = (branch==0)? bnq : (branch==1)? bnk : bnv;
    uint16_t* __restrict__ outp = (branch==0)? qs : (branch==1)? ks : vs;
    const uint16_t* __restrict__ wpl = wbr + (size_t)branch*442368;

    __shared__ __align__(16) uint16_t At[128][SA];      // padded A tile
    __shared__ __align__(16) uint16_t Bp[3][128][32];   // unpadded B planes (DMA dest)

    const int tid  = threadIdx.x;
    const int wv   = tid >> 6;
    const int lane = tid & 63;
    const int l15  = lane & 15;
    const int quad = lane >> 4;
    const int q8   = quad * 8;
    const int rg   = wv >> 1;            // rg0 -> t0,t1 ; rg1 -> t2,t3
    const int wcol = (wv & 1) * 64;
    const int wvu  = __builtin_amdgcn_readfirstlane(wv);   // wave-uniform SGPR

    f32x4 acc[4][4];
    #pragma unroll
    for (int it=0; it<4; ++it)
        #pragma unroll
        for (int jt=0; jt<4; ++jt) acc[it][jt] = (f32x4){0.f,0.f,0.f,0.f};

    // A staging: thread -> (trow = t*32+bnl, half of 32k), 16 fp32 each
    const int trow = tid >> 1, half = tid & 1;
    const int tA = trow >> 5, bnlA = trow & 31;
    const float* xrow = x + ((size_t)(tA*ROWS + bn0 + bnlA))*C_ + half*16;

    // B DMA: 24 wave-instrs per K-step (3 planes x 8 chunks of 16 rows);
    // wave wvu issues 6: gi = wvu*6+s -> plane p = gi>>3, chunk = gi&7.
    // lane l covers (row = chunk*16 + (l>>2), ks8 = l&3); dest = base + l*16.
    const uint16_t* bsrc[6];
    uint16_t* bdst[6];
    #pragma unroll
    for (int s=0; s<6; ++s) {
        const int gi = wvu*6 + s;
        const int p = gi >> 3, chunk = gi & 7;
        bsrc[s] = wpl + (size_t)p*147456
                + (size_t)(c0 + chunk*16 + (lane>>2))*C_ + (lane&3)*8;
        bdst[s] = &Bp[p][chunk*16][0];
    }

    // prefetch A(kt=0)
    float fe[16];
    #pragma unroll
    for (int s=0; s<4; ++s)
        *(float4*)&fe[4*s] = *(const float4*)(xrow + 4*s);

    for (int kt=0; kt<12; ++kt) {
        const int k0 = kt*32;
        __syncthreads();                  // prev-iter frag reads done
        // ---- B stage: async DMA straight to LDS (overlaps A split below) ----
        #pragma unroll
        for (int s=0; s<6; ++s) {
            __builtin_amdgcn_global_load_lds(
                (const __attribute__((address_space(1))) uint32_t*)(bsrc[s] + k0),
                (__attribute__((address_space(3))) uint32_t*)(bdst[s]),
                16, 0, 0);
        }
        // ---- A stage: split prefetched regs, write 3 planes ----
        {
            uint32_t hw[8], mw[8], lw[8];
            #pragma unroll
            for (int i=0; i<8; ++i) {
                const float s0 = fe[2*i], s1 = fe[2*i+1];
                const uint32_t h0 = __float_as_uint(s0) & 0xffff0000u;
                const uint32_t h1 = __float_as_uint(s1) & 0xffff0000u;
                const float r0 = s0 - __uint_as_float(h0);
                const float r1 = s1 - __uint_as_float(h1);
                const uint32_t m0 = __float_as_uint(r0) & 0xffff0000u;
                const uint32_t m1 = __float_as_uint(r1) & 0xffff0000u;
                const float p0 = r0 - __uint_as_float(m0);
                const float p1 = r1 - __uint_as_float(m1);
                hw[i] = (h0>>16) | h1;
                mw[i] = (m0>>16) | m1;
                lw[i] = (__float_as_uint(p0)>>16) | (__float_as_uint(p1) & 0xffff0000u);
            }
            *(uint4*)&At[trow][ 0 + half*16]     = make_uint4(hw[0],hw[1],hw[2],hw[3]);
            *(uint4*)&At[trow][ 0 + half*16 + 8] = make_uint4(hw[4],hw[5],hw[6],hw[7]);
            *(uint4*)&At[trow][32 + half*16]     = make_uint4(mw[0],mw[1],mw[2],mw[3]);
            *(uint4*)&At[trow][32 + half*16 + 8] = make_uint4(mw[4],mw[5],mw[6],mw[7]);
            *(uint4*)&At[trow][64 + half*16]     = make_uint4(lw[0],lw[1],lw[2],lw[3]);
            *(uint4*)&At[trow][64 + half*16 + 8] = make_uint4(lw[4],lw[5],lw[6],lw[7]);
        }
        __syncthreads();                  // drains DMA (vmcnt) + A writes (lgkm)

        // prefetch A(kt+1) — in flight across the whole MFMA burst
        if (kt < 11) {
            const float* xn = xrow + (kt+1)*32;
            #pragma unroll
            for (int s=0; s<4; ++s)
                *(float4*)&fe[4*s] = *(const float4*)(xn + 4*s);
        }

        // ---- fragments + 6-product MFMA (order identical to round 3) ----
        bf16x8 af[4][3];
        #pragma unroll
        for (int it=0; it<4; ++it) {
            const uint16_t* ar = &At[rg*64 + it*16 + l15][q8];
            af[it][0] = *(const bf16x8*)(ar);
            af[it][1] = *(const bf16x8*)(ar + 32);
            af[it][2] = *(const bf16x8*)(ar + 64);
        }
        #pragma unroll
        for (int jt=0; jt<4; ++jt) {
            const int brow = wcol + jt*16 + l15;
            const bf16x8 b0 = *(const bf16x8*)&Bp[0][brow][q8];
            const bf16x8 b1 = *(const bf16x8*)&Bp[1][brow][q8];
            const bf16x8 b2 = *(const bf16x8*)&Bp[2][brow][q8];
            #pragma unroll
            for (int it=0; it<4; ++it) {
                f32x4 a = acc[it][jt];
                a = __builtin_amdgcn_mfma_f32_16x16x32_bf16(af[it][0], b0, a, 0,0,0);
                a = __builtin_amdgcn_mfma_f32_16x16x32_bf16(af[it][0], b1, a, 0,0,0);
                a = __builtin_amdgcn_mfma_f32_16x16x32_bf16(af[it][1], b0, a, 0,0,0);
                a = __builtin_amdgcn_mfma_f32_16x16x32_bf16(af[it][0], b2, a, 0,0,0);
                a = __builtin_amdgcn_mfma_f32_16x16x32_bf16(af[it][1], b1, a, 0,0,0);
                a = __builtin_amdgcn_mfma_f32_16x16x32_bf16(af[it][2], b0, a, 0,0,0);
                acc[it][jt] = a;
            }
        }
    }

    // ---- epilogue: BN + LIF over t (round-3 verified logic) ----
    __syncthreads();
    float* vex = (float*)&At[0][0];      // [bnl 0..31][cl 0..127] f32 = 16 KB

    #define STORE_SP(tt, sp) do { \
        if (branch == 2) { \
            const int h2 = cg / 48, dd = cg - h2*48; \
            const int bng = bn0 + bnl; \
            outp[((((size_t)(tt)*B_ + (bng>>8))*H_ + h2)*D_ + dd)*N_ + (bng&255)] = (sp); \
        } else { \
            outp[((size_t)((tt)*ROWS + bn0 + bnl))*C_ + cg] = (sp); \
        } \
    } while(0)

    if (rg == 0) {
        #pragma unroll
        for (int jt=0; jt<4; ++jt) {
            const int cl = wcol + jt*16 + l15;
            const int cg = c0 + cl;
            const float g = bnp_[cg], be = bnp_[C_+cg], mu = bnp_[2*C_+cg], va = bnp_[3*C_+cg];
            const float scl = g * (float)(1.0 / sqrt((double)(va + 1e-5f)));
            #pragma unroll
            for (int a=0; a<2; ++a)
                #pragma unroll
                for (int r=0; r<4; ++r) {
                    const int bnl = a*16 + quad*4 + r;
                    const float y0 = (acc[a  ][jt][r] - mu)*scl + be;   // t0
                    const float y1 = (acc[a+2][jt][r] - mu)*scl + be;   // t1
                    float v = 0.f;
                    float h = v + (y0 - v)*0.5f;
                    STORE_SP(0, (h >= 1.0f) ? (uint16_t)0x3f80 : (uint16_t)0);
                    v = (h >= 1.0f) ? 0.f : h;
                    h = v + (y1 - v)*0.5f;
                    STORE_SP(1, (h >= 1.0f) ? (uint16_t)0x3f80 : (uint16_t)0);
                    v = (h >= 1.0f) ? 0.f : h;
                    vex[bnl*128 + cl] = v;
                }
        }
    }
    __syncthreads();
    if (rg == 1) {
        #pragma unroll
        for (int jt=0; jt<4; ++jt) {
            const int cl = wcol + jt*16 + l15;
            const int cg = c0 + cl;
            const float g = bnp_[cg], be = bnp_[C_+cg], mu = bnp_[2*C_+cg], va = bnp_[3*C_+cg];
            const float scl = g * (float)(1.0 / sqrt((double)(va + 1e-5f)));
            #pragma unroll
            for (int a=0; a<2; ++a)
                #pragma unroll
                for (int r=0; r<4; ++r) {
                    const int bnl = a*16 + quad*4 + r;
                    const float y2 = (acc[a  ][jt][r] - mu)*scl + be;   // t2
                    const float y3 = (acc[a+2][jt][r] - mu)*scl + be;   // t3
                    float v = vex[bnl*128 + cl];
                    float h = v + (y2 - v)*0.5f;
                    STORE_SP(2, (h >= 1.0f) ? (uint16_t)0x3f80 : (uint16_t)0);
                    v = (h >= 1.0f) ? 0.f : h;
                    h = v + (y3 - v)*0.5f;
                    STORE_SP(3, (h >= 1.0f) ? (uint16_t)0x3f80 : (uint16_t)0);
                }
        }
    }
    #undef STORE_SP
}

// ---------------------------------------------------------------------------
// K2: MFMA attention + attn-LIF (unchanged — verified)
// ---------------------------------------------------------------------------
__global__ __launch_bounds__(256, 2) void k_attn(
    const uint16_t* __restrict__ qs, const uint16_t* __restrict__ ks, const uint16_t* __restrict__ vs,
    const float* __restrict__ rel, uint16_t* __restrict__ as_)
{
    const int bh = blockIdx.x;
    const int b = bh >> 3, h = bh & 7;
    const int i0 = blockIdx.y * 128;

    __shared__ __align__(16) uint16_t qt[128][72];
    __shared__ __align__(16) uint16_t kt[32][72];
    __shared__ __align__(16) uint16_t vT[48][40];
    __shared__ __align__(16) uint16_t sh[3][128][40];
    __shared__ float tab_s[384];

    const int tid  = threadIdx.x;
    const int wv_  = tid >> 6;
    const int lane = tid & 63;
    const int l15  = lane & 15;
    const int quad = lane >> 4;
    const int w32  = wv_ * 32;
    const int q8   = quad * 8;

    for (int l = tid; l < 383; l += 256) tab_s[l] = rel[(size_t)(i0 + l)*H_ + h];
    {
        const uint4 z = make_uint4(0,0,0,0);
        { const int row = tid >> 1, seg = tid & 1;
          *(uint4*)&qt[row][48 + seg*8] = z; }
        if (tid < 64) { const int row = tid >> 1, seg = tid & 1;
          *(uint4*)&kt[row][48 + seg*8] = z; }
    }

    float vst[2][3][4];
    #pragma unroll
    for (int a=0;a<2;++a)
        #pragma unroll
        for (int e=0;e<3;++e)
            #pragma unroll
            for (int r=0;r<4;++r) vst[a][e][r]=0.f;

    for (int t=0; t<4; ++t) {
        const int tb = t*B_ + b;
        __syncthreads();
        #pragma unroll
        for (int rep=0; rep<3; ++rep) {
            const int l = rep*256 + tid;
            const int row = l / 6, seg = l - 6*row;
            *(uint4*)&qt[row][seg*8] =
                *(const uint4*)(qs + ((size_t)(tb*N_ + i0 + row))*C_ + h*D_ + seg*8);
        }

        f32x4 pacc[2][3];
        #pragma unroll
        for (int a=0;a<2;++a)
            #pragma unroll
            for (int e=0;e<3;++e) pacc[a][e] = (f32x4){0.f,0.f,0.f,0.f};

        for (int j0 = 0; j0 < 256; j0 += 32) {
            __syncthreads();
            if (tid < 192) {
                const int row = tid / 6, seg = tid - 6*row;
                *(uint4*)&kt[row][seg*8] =
                    *(const uint4*)(ks + ((size_t)(tb*N_ + j0 + row))*C_ + h*D_ + seg*8);
            } else {
                const int l = tid - 192;
                #pragma unroll
                for (int rep=0; rep<3; ++rep) {
                    const int e = rep*64 + l;
                    const int d = e >> 2, seg = e & 3;
                    *(uint4*)&vT[d][seg*8] =
                        *(const uint4*)(vs + (((size_t)(tb*H_ + h))*D_ + d)*N_ + j0 + seg*8);
                }
            }
            __syncthreads();

            f32x4 sacc[2][2];
            #pragma unroll
            for (int a=0;a<2;++a)
                #pragma unroll
                for (int c2=0;c2<2;++c2) sacc[a][c2] = (f32x4){0.f,0.f,0.f,0.f};
            bf16x8 qa[2][2];
            #pragma unroll
            for (int it=0; it<2; ++it)
                #pragma unroll
                for (int ks_=0; ks_<2; ++ks_)
                    qa[it][ks_] = *(const bf16x8*)&qt[w32 + it*16 + l15][ks_*32 + q8];
            #pragma unroll
            for (int jt=0; jt<2; ++jt) {
                #pragma unroll
                for (int ks_=0; ks_<2; ++ks_) {
                    const bf16x8 kb = *(const bf16x8*)&kt[jt*16 + l15][ks_*32 + q8];
                    #pragma unroll
                    for (int it=0; it<2; ++it)
                        sacc[it][jt] = __builtin_amdgcn_mfma_f32_16x16x32_bf16(
                            qa[it][ks_], kb, sacc[it][jt], 0, 0, 0);
                }
            }

            #pragma unroll
            for (int it=0; it<2; ++it)
                #pragma unroll
                for (int jt=0; jt<2; ++jt) {
                    const int jl = jt*16 + l15;
                    const int jg = j0 + jl;
                    #pragma unroll
                    for (int r=0; r<4; ++r) {
                        const int il = w32 + it*16 + quad*4 + r;
                        const float s = sacc[it][jt][r] + tab_s[il - jg + 255];
                        uint32_t hh, mm, ll;
                        split3(s, hh, mm, ll);
                        sh[0][il][jl] = (uint16_t)hh;
                        sh[1][il][jl] = (uint16_t)mm;
                        sh[2][il][jl] = (uint16_t)ll;
                    }
                }

            bf16x8 vb[3];
            #pragma unroll
            for (int dt=0; dt<3; ++dt)
                vb[dt] = *(const bf16x8*)&vT[dt*16 + l15][q8];
            #pragma unroll
            for (int it=0; it<2; ++it)
                #pragma unroll
                for (int p=0; p<3; ++p) {
                    const bf16x8 sa = *(const bf16x8*)&sh[p][w32 + it*16 + l15][q8];
                    #pragma unroll
                    for (int dt=0; dt<3; ++dt)
                        pacc[it][dt] = __builtin_amdgcn_mfma_f32_16x16x32_bf16(
                            sa, vb[dt], pacc[it][dt], 0, 0, 0);
                }
        }

        #pragma unroll
        for (int it=0; it<2; ++it)
            #pragma unroll
            for (int dt=0; dt<3; ++dt)
                #pragma unroll
                for (int r=0; r<4; ++r) {
                    const float xin = pacc[it][dt][r] * SCALE_F;
                    float v = vst[it][dt][r];
                    const float hh = v + (xin - v)*0.5f;
                    const uint16_t sp = (hh >= 1.0f) ? (uint16_t)0x3f80 : (uint16_t)0;
                    vst[it][dt][r] = (hh >= 1.0f) ? 0.f : hh;
                    const int ig = i0 + w32 + it*16 + quad*4 + r;
                    const int c  = h*D_ + dt*16 + l15;
                    as_[((size_t)(tb*N_ + ig))*C_ + c] = sp;
                }
    }
}

// ---------------------------------------------------------------------------
// K2.5: exact 3-way split of w_p (unchanged)
// ---------------------------------------------------------------------------
__global__ void k_wsplit(const float* __restrict__ wp,
                         uint16_t* __restrict__ wh, uint16_t* __restrict__ wm,
                         uint16_t* __restrict__ wl)
{
    const int idx = blockIdx.x*256 + threadIdx.x;
    uint32_t h, m, l;
    split3(wp[idx], h, m, l);
    wh[idx] = (uint16_t)h; wm[idx] = (uint16_t)m; wl[idx] = (uint16_t)l;
}

// ---------------------------------------------------------------------------
// K3: MFMA proj (unchanged — verified)
// ---------------------------------------------------------------------------
__global__ __launch_bounds__(256, 2) void k_proj(
    const uint16_t* __restrict__ as_,
    const uint16_t* __restrict__ wh, const uint16_t* __restrict__ wm,
    const uint16_t* __restrict__ wl,
    const float* __restrict__ bnp, float* __restrict__ out)
{
    const int r0 = blockIdx.x * 64;
    const int c0 = blockIdx.y * 96;

    __shared__ __align__(16) uint16_t At[4][64][40];
    __shared__ __align__(16) uint16_t Bt[3][96][40];

    const int tid  = threadIdx.x;
    const int wv_  = tid >> 6;
    const int lane = tid & 63;
    const int l15  = lane & 15;
    const int quad = lane >> 4;
    const int q8   = quad * 8;

    f32x4 acc[4][6];
    #pragma unroll
    for (int t=0;t<4;++t)
        #pragma unroll
        for (int nt=0;nt<6;++nt) acc[t][nt] = (f32x4){0.f,0.f,0.f,0.f};

    for (int kstep=0; kstep<12; ++kstep) {
        const int k0 = kstep*32;
        __syncthreads();
        #pragma unroll
        for (int rep=0; rep<4; ++rep) {
            const int l = rep*256 + tid;
            const int t = l >> 8, row = (l >> 2) & 63, seg = l & 3;
            *(uint4*)&At[t][row][seg*8] =
                *(const uint4*)(as_ + ((size_t)(t*ROWS + r0 + row))*C_ + k0 + seg*8);
        }
        for (int l = tid; l < 1152; l += 256) {
            const int p = l / 384, rem = l - 384*p;
            const int c = rem >> 2, seg = rem & 3;
            const uint16_t* src = (p==0)? wh : (p==1)? wm : wl;
            *(uint4*)&Bt[p][c][seg*8] =
                *(const uint4*)(src + (size_t)(c0 + c)*C_ + k0 + seg*8);
        }
        __syncthreads();

        bf16x8 af[4];
        #pragma unroll
        for (int t=0;t<4;++t)
            af[t] = *(const bf16x8*)&At[t][wv_*16 + l15][q8];
        #pragma unroll
        for (int nt=0; nt<6; ++nt) {
            #pragma unroll
            for (int p=0; p<3; ++p) {
                const bf16x8 bf_ = *(const bf16x8*)&Bt[p][nt*16 + l15][q8];
                #pragma unroll
                for (int t=0;t<4;++t)
                    acc[t][nt] = __builtin_amdgcn_mfma_f32_16x16x32_bf16(
                        af[t], bf_, acc[t][nt], 0, 0, 0);
            }
        }
    }

    #pragma unroll
    for (int nt=0; nt<6; ++nt) {
        const int c = c0 + nt*16 + l15;
        const float g = bnp[c], be = bnp[C_+c], mu = bnp[2*C_+c], va = bnp[3*C_+c];
        const float scl = g * (float)(1.0 / sqrt((double)(va + 1e-5f)));
        #pragma unroll
        for (int r=0; r<4; ++r) {
            const int rg = r0 + wv_*16 + quad*4 + r;
            float v = 0.f;
            #pragma unroll
            for (int t=0; t<4; ++t) {
                const float y  = (acc[t][nt][r] - mu)*scl + be;
                const float hh = v + (y - v)*0.5f;
                const float sp = (hh >= 1.0f) ? 1.0f : 0.f;
                v = (hh >= 1.0f) ? 0.f : hh;
                out[((size_t)(t*ROWS + rg))*C_ + c] = sp;
            }
        }
    }
}

extern "C" void kernel_launch(void* const* d_in, const int* in_sizes, int n_in,
                              void* d_out, int out_size, void* d_ws, size_t ws_size,
                              hipStream_t stream) {
    const float* x   = (const float*)d_in[0];
    const float* wq  = (const float*)d_in[1];
    const float* wk  = (const float*)d_in[2];
    const float* wv  = (const float*)d_in[3];
    const float* wp  = (const float*)d_in[4];
    const float* bnq = (const float*)d_in[5];
    const float* bnk = (const float*)d_in[6];
    const float* bnv = (const float*)d_in[7];
    const float* bnp = (const float*)d_in[8];
    const float* rel = (const float*)d_in[9];
    float* out = (float*)d_out;
    uint8_t* ws = (uint8_t*)d_ws;
    uint16_t* qs  = (uint16_t*)(ws + QS_OFF);
    uint16_t* ks  = (uint16_t*)(ws + KS_OFF);
    uint16_t* vs  = (uint16_t*)(ws + VS_OFF);
    uint16_t* as_ = (uint16_t*)(ws + AS_OFF);
    uint16_t* wbr = (uint16_t*)(ws + AS_OFF);      // branch w-planes: dead once k_attn writes as_
    uint16_t* wh  = (uint16_t*)(ws + WH_OFF);
    uint16_t* wm  = (uint16_t*)(ws + WM_OFF);
    uint16_t* wl  = (uint16_t*)(ws + WL_OFF);

    k_wsplit3<<<dim3(576, 3), 256, 0, stream>>>(wq, wk, wv, wbr);
    k_qkv_v6 <<<dim3(9, 256), 256, 0, stream>>>(x, wbr, bnq, bnk, bnv, qs, ks, vs);
    k_attn   <<<dim3(256, 2), 256, 0, stream>>>(qs, ks, vs, rel, as_);
    k_wsplit <<<dim3(576),    256, 0, stream>>>(wp, wh, wm, wl);
    k_proj   <<<dim3(128, 4), 256, 0, stream>>>(as_, wh, wm, wl, bnp, out);
}